// Round 3
// baseline (652.108 us; speedup 1.0000x reference)
//
#include <hip/hip_runtime.h>
#include <hip/hip_fp16.h>

// DepTreeLSTM on MI355X — weight-stationary fused level GEMM.
// Per (direction,level): C[row, col] = [x_node(320) || h_src(64)] @ B(384x256),
// B cols interleaved per hidden unit: col = 4*u + role (0:i,1:o,2:u,3:f).
// Persistent blocks: each block owns (side, 16-unit quarter nq), keeps its
// 64-col B slice in 192 VGPRs for the whole dispatch, and strides over
// 64-row M-chunks. K-loop: 12 direct global->VGPR A-fragment gathers + 48
// MFMA (16x16x32 f16), NO LDS, NO barriers. Epilogue: quad 4x4 transpose
// (shfl_xor) gives each lane one row's I/O/U/F -> LSTM cell -> h,c state
// (fp16) or final out (fp32). Root = 4 rows/pair: [x||h7],[x||h9],[x||0],
// [0||0]; iou = r0+r1-r2 (in-lane reg combine), f7/f9 from role-3 lane.

typedef _Float16 f16x8 __attribute__((ext_vector_type(8)));
typedef float f32x4 __attribute__((ext_vector_type(4)));

struct Side {
    const _Float16* B;       // 256x384 fp16, [col][k], cols iouf-interleaved
    const float* b_iou;      // 192
    const float* b_f;        // 64
    _Float16* h;             // [N][64]
    _Float16* c;             // [N][64]
    int rp_shift, is_root, nchunks;
    int4 pos, hpos, ocol;
};

__device__ __forceinline__ int sel4(int4 v, int s) {
    return s == 0 ? v.x : s == 1 ? v.y : s == 2 ? v.z : v.w;
}
__device__ __forceinline__ float sigm(float x) { return 1.f / (1.f + __expf(-x)); }
__device__ __forceinline__ float ftanh(float x) {
    float a = __expf(-2.f * fabsf(x));
    return copysignf((1.f - a) / (1.f + a), x);
}

// ---- pack weights to fp16 [dir][col(256)][k(384)], iouf-interleaved cols ----
__global__ __launch_bounds__(256) void pack_weights(
    const float* __restrict__ Wi_u, const float* __restrict__ Ui_u,
    const float* __restrict__ Wf_u, const float* __restrict__ Uf_u,
    const float* __restrict__ Wi_d, const float* __restrict__ Ui_d,
    const float* __restrict__ Wf_d, const float* __restrict__ Uf_d,
    _Float16* __restrict__ Bt, _Float16* __restrict__ zp)
{
    int idx = blockIdx.x * 256 + threadIdx.x;   // 2*256*384 = 196608
    if (idx < 512) zp[idx] = (_Float16)0.f;
    int d   = idx / 98304;
    int rem = idx % 98304;
    int col = rem / 384;
    int k   = rem % 384;
    int u = col >> 2, r = col & 3;
    const float* Wi = d ? Wi_d : Wi_u;
    const float* Ui = d ? Ui_d : Ui_u;
    const float* Wf = d ? Wf_d : Wf_u;
    const float* Uf = d ? Uf_d : Uf_u;
    float v;
    if (r < 3) v = (k < 320) ? Wi[k * 192 + r * 64 + u]
                             : Ui[(k - 320) * 192 + r * 64 + u];
    else       v = (k < 320) ? Wf[k * 64 + u]
                             : Uf[(k - 320) * 64 + u];
    Bt[idx] = (_Float16)v;
}

// ---- fuse+convert embeddings to fp16 x16[B*T][320] ----
__global__ __launch_bounds__(256) void build_x16(
    const float* __restrict__ tok, const float* __restrict__ oh,
    const float* __restrict__ dep, _Float16* __restrict__ x16)
{
    int idx = blockIdx.x * 256 + threadIdx.x;   // 16384 bt * 40 granules
    int bt = idx / 40, g = idx % 40;
    const float* src = (g < 32) ? tok + (size_t)bt * 256 + g * 8
                     : (g < 36) ? oh  + (size_t)bt * 32 + (g - 32) * 8
                                : dep + (size_t)bt * 32 + (g - 36) * 8;
    float4 f0 = *(const float4*)src;
    float4 f1 = *(const float4*)(src + 4);
    f16x8 v;
    v[0] = (_Float16)f0.x; v[1] = (_Float16)f0.y;
    v[2] = (_Float16)f0.z; v[3] = (_Float16)f0.w;
    v[4] = (_Float16)f1.x; v[5] = (_Float16)f1.y;
    v[6] = (_Float16)f1.z; v[7] = (_Float16)f1.w;
    *(f16x8*)(x16 + (size_t)bt * 320 + g * 8) = v;
}

__global__ __launch_bounds__(256, 2) void fused_level(
    const _Float16* __restrict__ x16,
    const int* __restrict__ nb, const int* __restrict__ nt,
    const _Float16* __restrict__ zp,
    float* __restrict__ out,
    int Gu, Side up, Side dn)
{
    const int b = blockIdx.x;
    const bool isup = b < Gu;
    const Side S = isup ? up : dn;
    const int gsz = isup ? Gu : ((int)gridDim.x - Gu);
    const int lb  = isup ? b : b - Gu;
    const int nq = lb & 3;
    const int c0 = lb >> 2;
    const int cstep = gsz >> 2;

    const int tid = threadIdx.x, lane = tid & 63, w = tid >> 6;
    const int l15 = lane & 15, qd = lane >> 4, role = lane & 3, qu = l15 >> 2;
    const int mask = (1 << S.rp_shift) - 1;

    // ---- B fragments, register-resident for the whole dispatch ----
    f16x8 bfr[12][4];
    #pragma unroll
    for (int s = 0; s < 12; ++s)
        #pragma unroll
        for (int j = 0; j < 4; ++j) {
            int col = nq * 64 + j * 16 + l15;
            bfr[s][j] = *(const f16x8*)(S.B + (size_t)col * 384 + s * 32 + qd * 8);
        }

    for (int ch = c0; ch < S.nchunks; ch += cstep) {
        // ---- A-fragment pointers for this lane's row (l15 of wave tile) ----
        int rowA  = ch * 64 + w * 16 + l15;
        int pairA = rowA >> S.rp_shift;
        int slotA = rowA & mask;
        int posA  = sel4(S.pos, slotA);
        int hpA   = sel4(S.hpos, slotA);
        bool zx   = S.is_root && (slotA == 3);
        int nodeA = pairA * 16 + posA;
        const _Float16* xp = zx ? zp
            : x16 + ((size_t)nb[nodeA] * 512 + nt[nodeA]) * 320;
        const _Float16* hp = (hpA < 0) ? zp
            : S.h + (size_t)(pairA * 16 + hpA) * 64;

        f32x4 acc[4];
        #pragma unroll
        for (int j = 0; j < 4; ++j) acc[j] = (f32x4){0.f, 0.f, 0.f, 0.f};

        #pragma unroll
        for (int s = 0; s < 12; ++s) {
            f16x8 af = (s < 10)
                ? *(const f16x8*)(xp + s * 32 + qd * 8)
                : *(const f16x8*)(hp + (s - 10) * 32 + qd * 8);
            #pragma unroll
            for (int j = 0; j < 4; ++j)
                acc[j] = __builtin_amdgcn_mfma_f32_16x16x32_f16(
                    af, bfr[s][j], acc[j], 0, 0, 0);
        }

        // ---- epilogue ----
        if (!S.is_root) {
            int rowE  = ch * 64 + w * 16 + qd * 4 + role;
            int pairE = rowE >> S.rp_shift;
            int slotE = rowE & mask;
            int posE  = sel4(S.pos, slotE);
            int hpE   = sel4(S.hpos, slotE);
            int ocE   = sel4(S.ocol, slotE);
            #pragma unroll
            for (int j = 0; j < 4; ++j) {
                int u = nq * 16 + j * 4 + qu;
                // quad 4x4 transpose: lane(role r) ends with row(qd*4+r)'s IOUF
                float v0 = acc[j][0], v1 = acc[j][1],
                      v2 = acc[j][2], v3 = acc[j][3];
                float s0 = __shfl_xor(v1, 1), s1 = __shfl_xor(v0, 1),
                      s2 = __shfl_xor(v3, 1), s3 = __shfl_xor(v2, 1);
                bool e1 = (role & 1) == 0;
                float u0 = e1 ? v0 : s0, u1 = e1 ? s1 : v1,
                      u2 = e1 ? v2 : s2, u3 = e1 ? s3 : v3;
                float q0 = __shfl_xor(u2, 2), q1 = __shfl_xor(u3, 2),
                      q2 = __shfl_xor(u0, 2), q3 = __shfl_xor(u1, 2);
                bool e2 = (role & 2) == 0;
                float I = (e2 ? u0 : q0) + S.b_iou[u];
                float O = (e2 ? u1 : q1) + S.b_iou[64 + u];
                float U = (e2 ? q2 : u2) + S.b_iou[128 + u];
                float F = (e2 ? q3 : u3) + S.b_f[u];
                float cin = (hpE >= 0)
                    ? (float)S.c[((size_t)pairE * 16 + hpE) * 64 + u] : 0.f;
                float cn = sigm(I) * ftanh(U) + sigm(F) * cin;
                float h  = sigm(O) * ftanh(cn);
                if (ocE >= 0) {
                    out[(size_t)pairE * 192 + ocE + u] = h;
                } else {
                    size_t nd = ((size_t)pairE * 16 + posE) * 64 + u;
                    S.h[nd] = (_Float16)h;
                    S.c[nd] = (_Float16)cn;
                }
            }
        } else {
            int pairE = (ch * 64 + w * 16 + qd * 4) >> 2;
            int qb = lane & ~3;
            #pragma unroll
            for (int j = 0; j < 4; ++j) {
                int u = nq * 16 + j * 4 + qu;
                float pre = acc[j][0] + acc[j][1] - acc[j][2];
                float I  = __shfl(pre, qb + 0);
                float O  = __shfl(pre, qb + 1);
                float Uu = __shfl(pre, qb + 2);
                float F7 = __shfl(acc[j][0], qb + 3);
                float F9 = __shfl(acc[j][1], qb + 3);
                if (role == 0) {
                    float c7 = (float)S.c[((size_t)pairE * 16 + 7) * 64 + u];
                    float c9 = (float)S.c[((size_t)pairE * 16 + 9) * 64 + u];
                    float cn = sigm(I + S.b_iou[u]) * ftanh(Uu + S.b_iou[128 + u])
                             + sigm(F7 + S.b_f[u]) * c7
                             + sigm(F9 + S.b_f[u]) * c9;
                    float h = sigm(O + S.b_iou[64 + u]) * ftanh(cn);
                    out[(size_t)pairE * 192 + S.ocol.x + u] = h;
                }
            }
        }
    }
}

extern "C" void kernel_launch(void* const* d_in, const int* in_sizes, int n_in,
                              void* d_out, int out_size, void* d_ws, size_t ws_size,
                              hipStream_t stream)
{
    const float* tok  = (const float*)d_in[0];
    const float* ohp  = (const float*)d_in[1];
    const float* dep  = (const float*)d_in[2];
    const int*   nb   = (const int*)d_in[3];
    const int*   nt   = (const int*)d_in[4];
    const float* Wi_u = (const float*)d_in[13];
    const float* Ui_u = (const float*)d_in[14];
    const float* bi_u = (const float*)d_in[15];
    const float* Wf_u = (const float*)d_in[16];
    const float* Uf_u = (const float*)d_in[17];
    const float* bf_u = (const float*)d_in[18];
    const float* Wi_d = (const float*)d_in[19];
    const float* Ui_d = (const float*)d_in[20];
    const float* bi_d = (const float*)d_in[21];
    const float* Wf_d = (const float*)d_in[22];
    const float* Uf_d = (const float*)d_in[23];
    const float* bf_d = (const float*)d_in[24];

    char* ws = (char*)d_ws;
    _Float16* Bt   = (_Float16*)(ws);                          // 384 KB
    _Float16* zp   = (_Float16*)(ws + (512 << 10));            // 1 KB zeros
    _Float16* x16  = (_Float16*)(ws + (1  << 20));             // 10.5 MB
    _Float16* h_u  = (_Float16*)(ws + (16 << 20));
    _Float16* c_u  = (_Float16*)(ws + (48 << 20));
    _Float16* h_d  = (_Float16*)(ws + (80 << 20));
    _Float16* c_d  = (_Float16*)(ws + (112 << 20));
    float* out = (float*)d_out;

    pack_weights<<<768, 256, 0, stream>>>(Wi_u, Ui_u, Wf_u, Uf_u,
                                          Wi_d, Ui_d, Wf_d, Uf_d, Bt, zp);
    build_x16<<<2560, 256, 0, stream>>>(tok, ohp, dep, x16);

    const _Float16* Bu = Bt;
    const _Float16* Bd = Bt + 98304;
    int4 none = {-1, -1, -1, -1};

    // L0: up {pos0,15, h=0} C=512 | dn {pos8, h=0} C=256
    {
        Side U = {Bu, bi_u, bf_u, h_u, c_u, 1, 0, 512, {0,15,0,0}, none, none};
        Side D = {Bd, bi_d, bf_d, h_d, c_d, 0, 0, 256, {8,0,0,0}, none, none};
        fused_level<<<512, 256, 0, stream>>>(x16, nb, nt, zp, out, 340, U, D);
    }
    // L1..L6: both sides C=512
    for (int t = 1; t <= 6; ++t) {
        Side U = {Bu, bi_u, bf_u, h_u, c_u, 1, 0, 512,
                  {t, 15 - t, 0, 0}, {t - 1, 16 - t, -1, -1}, none};
        Side D = {Bd, bi_d, bf_d, h_d, c_d, 1, 0, 512,
                  {8 - t, 8 + t, 0, 0}, {9 - t, 7 + t, -1, -1}, none};
        fused_level<<<512, 256, 0, stream>>>(x16, nb, nt, zp, out, 256, U, D);
    }
    // L7: up {pos7} C=256 | dn {pos1 -> state, pos15 -> out[128..]} C=512
    {
        Side U = {Bu, bi_u, bf_u, h_u, c_u, 0, 0, 256,
                  {7, 0, 0, 0}, {6, -1, -1, -1}, none};
        Side D = {Bd, bi_d, bf_d, h_d, c_d, 1, 0, 512,
                  {1, 15, 0, 0}, {2, 14, -1, -1}, {-1, 128, -1, -1}};
        fused_level<<<512, 256, 0, stream>>>(x16, nb, nt, zp, out, 172, U, D);
    }
    // L8: up root (4 rows/pair -> out[0..63]) C=1024 | dn {pos0 -> out[64..]} C=256
    {
        Side U = {Bu, bi_u, bf_u, h_u, c_u, 2, 1, 1024,
                  {8, 8, 8, 8}, {7, 9, -1, -1}, {0, 0, 0, 0}};
        Side D = {Bd, bi_d, bf_d, h_d, c_d, 0, 0, 256,
                  {0, 0, 0, 0}, {1, -1, -1, -1}, {64, -1, -1, -1}};
        fused_level<<<512, 256, 0, stream>>>(x16, nb, nt, zp, out, 408, U, D);
    }
    (void)in_sizes; (void)n_in; (void)out_size; (void)ws_size;
}